// Round 2
// 381.390 us; speedup vs baseline: 1.0264x; 1.0264x over previous
//
#include <hip/hip_runtime.h>
#include <cmath>
#include <cstddef>

#define BATCH 8
#define CH    3
#define HH    512
#define WW    512
#define NSLOT 7
#define HWX   (HH*WW)

__device__ __host__ __forceinline__ int refl(int i, int n) {
    i = i < 0 ? -i : i;
    return i >= n ? 2 * n - 2 - i : i;
}

// ---------------- compile-time Gaussian weights -----------------
constexpr double cexp_(double x) {           // e^x for x in [-13, 0]
    double r = x / 64.0, term = 1.0, s = 1.0;
    for (int i = 1; i < 26; ++i) { term *= r / i; s += term; }
    for (int j = 0; j < 6; ++j) s *= s;      // s = (e^{x/64})^64
    return s;
}

// h-pass weights: real taps at [8, 8+KS), zeros elsewhere (compile-time indexed -> literals)
template<int KS> struct WArr { float w[KS + 16]; };

template<int KS>
constexpr WArr<KS> make_w(double sg) {
    WArr<KS> a{};
    double tmp[KS] = {};
    double sum = 0.0;
    for (int t = 0; t < KS; ++t) {
        const double ax = (double)(t - KS / 2);
        tmp[t] = cexp_(-(ax * ax) / (2.0 * sg * sg));
        sum += tmp[t];
    }
    for (int i = 0; i < KS + 16; ++i) a.w[i] = 0.0f;
    for (int t = 0; t < KS; ++t) a.w[8 + t] = (float)(tmp[t] / sum);
    return a;
}

__device__ constexpr WArr<7>   CW0 = make_w<7>(0.6);
__device__ constexpr WArr<9>   CW1 = make_w<9>(1.2);
__device__ constexpr WArr<17>  CW2 = make_w<17>(2.4);
__device__ constexpr WArr<31>  CW3 = make_w<31>(4.8);
__device__ constexpr WArr<59>  CW4 = make_w<59>(9.6);
__device__ constexpr WArr<117> CW5 = make_w<117>(19.2);

// v-pass weights: 16 leading zeros, taps at [16,16+KS), zero-padded to TPAD+16
// (TPAD = KS+15 rounded up to x16; extra iterations multiply by exact 0.0f)
template<int KS> struct VWArr {
    static constexpr int TPAD = (KS + 30) & ~15;
    float w[TPAD + 16];
};

template<int KS>
constexpr VWArr<KS> make_vw(double sg) {
    VWArr<KS> a{};
    double tmp[KS] = {};
    double sum = 0.0;
    for (int t = 0; t < KS; ++t) {
        const double ax = (double)(t - KS / 2);
        tmp[t] = cexp_(-(ax * ax) / (2.0 * sg * sg));
        sum += tmp[t];
    }
    for (int i = 0; i < VWArr<KS>::TPAD + 16; ++i) a.w[i] = 0.0f;
    for (int t = 0; t < KS; ++t) a.w[16 + t] = (float)(tmp[t] / sum);
    return a;
}

__device__ constexpr VWArr<7>   VW0 = make_vw<7>(0.6);
__device__ constexpr VWArr<9>   VW1 = make_vw<9>(1.2);
__device__ constexpr VWArr<17>  VW2 = make_vw<17>(2.4);
__device__ constexpr VWArr<31>  VW3 = make_vw<31>(4.8);
__device__ constexpr VWArr<59>  VW4 = make_vw<59>(9.6);
__device__ constexpr VWArr<117> VW5 = make_vw<117>(19.2);

// ---------------- vertical blur: 16 rows x float4 per thread ----------------
// Sliding 32-entry weight window (compile-time indexed -> SGPRs, refilled by
// 16 uniform s_loads per chunk). 16 independent dwordx4 loads in flight/chunk.
template<int KS, int PD>
__device__ __forceinline__ void vpass16(const float4* __restrict__ img4,
                                        float4* __restrict__ dst,
                                        int xt, int y0, const float* __restrict__ vw)
{
    constexpr int TPAD = (KS + 30) & ~15;
    float4 acc[16];
#pragma unroll
    for (int j = 0; j < 16; ++j) acc[j] = make_float4(0.f, 0.f, 0.f, 0.f);

    float ww[16];                      // window low half: ww[m] == vw[tb+m]
#pragma unroll
    for (int m = 0; m < 16; ++m) ww[m] = vw[m];

#pragma unroll 1
    for (int tb = 0; tb < TPAD; tb += 16) {
        float wn[16];                  // window high half: wn[k] == vw[tb+16+k]
#pragma unroll
        for (int k = 0; k < 16; ++k) wn[k] = vw[tb + 16 + k];
#pragma unroll
        for (int k = 0; k < 16; ++k) {
            const int yi = refl(y0 - PD + tb + k, HH);
            const float4 v = img4[(size_t)yi * (WW / 4) + xt];
#pragma unroll
            for (int j = 0; j < 16; ++j) {
                const int mi = 16 + k - j;               // 1..31, compile-time
                const float wt = (mi < 16) ? ww[mi] : wn[mi - 16];
                acc[j].x = fmaf(wt, v.x, acc[j].x);
                acc[j].y = fmaf(wt, v.y, acc[j].y);
                acc[j].z = fmaf(wt, v.z, acc[j].z);
                acc[j].w = fmaf(wt, v.w, acc[j].w);
            }
        }
#pragma unroll
        for (int m = 0; m < 16; ++m) ww[m] = wn[m];      // shift window
    }
#pragma unroll
    for (int j = 0; j < 16; ++j) dst[(size_t)(y0 + j) * (WW / 4) + xt] = acc[j];
}

__global__ __launch_bounds__(128) void vpass6_kernel(const float* __restrict__ img,
                                                     float* __restrict__ out)
{
    const int s  = blockIdx.x;
    const int xt = threadIdx.x;              // 0..127 (float4 col)
    const int y0 = blockIdx.y * 16;
    const int bc = blockIdx.z;
    const int b = bc / CH, c = bc - b * CH;
    const float4* img4 = (const float4*)img + (size_t)bc * (HWX / 4);
    float4* dst = (float4*)out + ((size_t)((b * NSLOT + s + 1) * CH) + c) * (HWX / 4);
    switch (s) {
        case 0: vpass16<  7,  3>(img4, dst, xt, y0, VW0.w); break;
        case 1: vpass16<  9,  4>(img4, dst, xt, y0, VW1.w); break;
        case 2: vpass16< 17,  8>(img4, dst, xt, y0, VW2.w); break;
        case 3: vpass16< 31, 15>(img4, dst, xt, y0, VW3.w); break;
        case 4: vpass16< 59, 29>(img4, dst, xt, y0, VW4.w); break;
        default:vpass16<117, 58>(img4, dst, xt, y0, VW5.w); break;
    }
}

// ---------------- horizontal blur: 4 px/thread, b128 rolling window, literal weights -------
template<int KS>
__device__ __forceinline__ float4 hblur4c(const float* __restrict__ lrow, int xt,
                                          const WArr<KS>& W)
{
    constexpr int NT = (KS + 3) & ~3;
    const float4* l4 = (const float4*)lrow;
    float cb[16];
    {
        float4 t0 = l4[xt + 0];
        cb[0] = t0.x; cb[1] = t0.y; cb[2] = t0.z; cb[3] = t0.w;
        float4 t1 = l4[xt + 1];
        cb[4] = t1.x; cb[5] = t1.y; cb[6] = t1.z; cb[7] = t1.w;
    }
    float a[4] = {0.f, 0.f, 0.f, 0.f};
#pragma unroll
    for (int tb = 0; tb < NT; tb += 4) {
        const int ls = ((tb >> 2) + 2) & 3;
        float4 tn = l4[xt + (tb >> 2) + 2];          // overshoot covered by LEN pad
        cb[ls * 4 + 0] = tn.x; cb[ls * 4 + 1] = tn.y;
        cb[ls * 4 + 2] = tn.z; cb[ls * 4 + 3] = tn.w;
#pragma unroll
        for (int tt = 0; tt < 4; ++tt) {
            const float wt = W.w[8 + tb + tt];       // compile-time constant
#pragma unroll
            for (int j = 0; j < 4; ++j) {
                const int q    = tt + j;             // 0..6
                const int slot = ((tb >> 2) + (q >> 2)) & 3;
                a[j] = fmaf(wt, cb[slot * 4 + (q & 3)], a[j]);
            }
        }
    }
    return make_float4(a[0], a[1], a[2], a[3]);
}

// ---------------- fused h-pass + DoG diff, in-place on out ---------------------------------
// LDS row layout (floats), img row NOT staged (gp read direct from global):
// s:      0     1     2     3     4     5
// OFF:    0   524  1052  1588  2136  2712     (all OFF % 4 == 0 for b128 reads)
// LEN:  524   528   536   548   576   636     (= NT + 516)
#define LDSROW 3348   // 13392 B/row, 26784 B/block -> 6 blocks/CU (24 waves)

// Vectorized staging: bulk 512 floats as one float4/thread, scalar halo loops.
template<int OFF, int LEN, int PD>
__device__ __forceinline__ void stage_row(float* __restrict__ L,
                                          const float* __restrict__ g, int xt)
{
    const float4 v = ((const float4*)g)[xt];
    if constexpr ((PD & 3) == 0) {
        ((float4*)(L + OFF + PD))[xt] = v;
    } else {
        float* d = L + OFF + PD + 4 * xt;
        d[0] = v.x; d[1] = v.y; d[2] = v.z; d[3] = v.w;
    }
    if (xt < PD) L[OFF + xt] = g[PD - xt];                        // left reflect
    for (int i = PD + 512 + xt; i < LEN; i += 128)                // right reflect (<=1 iter)
        L[OFF + i] = g[2 * WW - 2 - (i - PD)];
}

__device__ __forceinline__ float4 f4sub(float4 a, float4 b) {
    return make_float4(a.x - b.x, a.y - b.y, a.z - b.z, a.w - b.w);
}

__global__ __launch_bounds__(256) void hdiff6_kernel(const float* __restrict__ img,
                                                     float* __restrict__ out)
{
    __shared__ __align__(16) float lds[2][LDSROW];
    const int xt = threadIdx.x;              // 0..127
    const int r  = threadIdx.y;              // 0..1
    const int y  = blockIdx.y * 2 + r;
    const int bc = blockIdx.z;
    const int b = bc / CH, c = bc - b * CH;
    float* L = lds[r];

    // stage the 6 v-blurred rows from out slots 1..6 (bulk float4 + scalar halos)
    const size_t rowoff = (size_t)y * WW;
    constexpr size_t SSTR = (size_t)CH * HWX;     // slot stride in floats
    const float* g1 = out + ((size_t)((b * NSLOT + 1) * CH) + c) * HWX + rowoff;
    stage_row<   0, 524,  3>(L, g1,            xt);
    stage_row< 524, 528,  4>(L, g1 + 1 * SSTR, xt);
    stage_row<1052, 536,  8>(L, g1 + 2 * SSTR, xt);
    stage_row<1588, 548, 15>(L, g1 + 3 * SSTR, xt);
    stage_row<2136, 576, 29>(L, g1 + 4 * SSTR, xt);
    stage_row<2712, 636, 58>(L, g1 + 5 * SSTR, xt);
    __syncthreads();

    float4* out4 = (float4*)out;
    const size_t pbase = (size_t)y * (WW / 4) + xt;
#define OSL(s) (out4 + ((size_t)((b * NSLOT + (s)) * CH) + c) * (HWX / 4) + pbase)

    // g0 = img, read direct from global (own pixels only, no halo needed)
    float4 gp = ((const float4*)(img + (size_t)bc * HWX + rowoff))[xt];
    float4 g;
    g = hblur4c<  7>(L +    0, xt, CW0); *OSL(0) = f4sub(g, gp); gp = g;
    g = hblur4c<  9>(L +  524, xt, CW1); *OSL(1) = f4sub(g, gp); gp = g;
    g = hblur4c< 17>(L + 1052, xt, CW2); *OSL(2) = f4sub(g, gp); gp = g;
    g = hblur4c< 31>(L + 1588, xt, CW3); *OSL(3) = f4sub(g, gp); gp = g;
    g = hblur4c< 59>(L + 2136, xt, CW4); *OSL(4) = f4sub(g, gp); gp = g;
    g = hblur4c<117>(L + 2712, xt, CW5); *OSL(5) = f4sub(g, gp);
    *OSL(6) = g;
#undef OSL
}

// ---------------- host ----------------------------------------------------------------------
extern "C" void kernel_launch(void* const* d_in, const int* in_sizes, int n_in,
                              void* d_out, int out_size, void* d_ws, size_t ws_size,
                              hipStream_t stream) {
    const float* img = (const float*)d_in[0];
    float* out = (float*)d_out;

    // pass 1: vertical blur img -> out slots 1..6 (weights in .rodata, s_load window)
    const dim3 bv(128, 1), gv(6, HH / 16, BATCH * CH);
    hipLaunchKernelGGL(vpass6_kernel, gv, bv, 0, stream, img, out);

    // pass 2: horizontal blur + DoG diff chain, in-place on out
    const dim3 bh(128, 2), gh(1, HH / 2, BATCH * CH);
    hipLaunchKernelGGL(hdiff6_kernel, gh, bh, 0, stream, img, out);
}

// Round 3
// 366.903 us; speedup vs baseline: 1.0670x; 1.0395x over previous
//
#include <hip/hip_runtime.h>
#include <cmath>
#include <cstddef>

#define BATCH 8
#define CH    3
#define HH    512
#define WW    512
#define NSLOT 7
#define HWX   (HH*WW)

__device__ __host__ __forceinline__ int refl(int i, int n) {
    i = i < 0 ? -i : i;
    return i >= n ? 2 * n - 2 - i : i;
}

// ---------------- compile-time Gaussian weights -----------------
constexpr double cexp_(double x) {           // e^x for x in [-13, 0]
    double r = x / 64.0, term = 1.0, s = 1.0;
    for (int i = 1; i < 26; ++i) { term *= r / i; s += term; }
    for (int j = 0; j < 6; ++j) s *= s;      // s = (e^{x/64})^64
    return s;
}

// h-pass weights: effective size KSE = KS + Z (Z zero taps prepended so the
// staged row's left pad is a multiple of 4 floats -> all-b128 LDS staging).
// Real taps at [8+Z, 8+KSE), zeros elsewhere; compile-time indexed -> literals.
template<int KSE> struct WArr { float w[KSE + 16]; };

template<int KSE, int KS>
constexpr WArr<KSE> make_wz(double sg) {
    WArr<KSE> a{};
    double tmp[KS] = {};
    double sum = 0.0;
    for (int t = 0; t < KS; ++t) {
        const double ax = (double)(t - KS / 2);
        tmp[t] = cexp_(-(ax * ax) / (2.0 * sg * sg));
        sum += tmp[t];
    }
    for (int i = 0; i < KSE + 16; ++i) a.w[i] = 0.0f;
    constexpr int Z = KSE - KS;
    for (int t = 0; t < KS; ++t) a.w[8 + Z + t] = (float)(tmp[t] / sum);
    return a;
}

// per scale: KS {7,9,17,31,59,117}, PD=KS/2 {3,4,8,15,29,58}
// PDA = round-up-4 {4,4,8,16,32,60}; Z = PDA-PD {1,0,0,1,3,2}; KSE = KS+Z
__device__ constexpr WArr<8>   CW0 = make_wz<8,   7>(0.6);
__device__ constexpr WArr<9>   CW1 = make_wz<9,   9>(1.2);
__device__ constexpr WArr<17>  CW2 = make_wz<17, 17>(2.4);
__device__ constexpr WArr<32>  CW3 = make_wz<32, 31>(4.8);
__device__ constexpr WArr<62>  CW4 = make_wz<62, 59>(9.6);
__device__ constexpr WArr<119> CW5 = make_wz<119,117>(19.2);

// v-pass weights: 16 leading zeros, taps at [16,16+KS), zero-padded to TPAD+16
template<int KS> struct VWArr {
    static constexpr int TPAD = (KS + 30) & ~15;
    float w[TPAD + 16];
};

template<int KS>
constexpr VWArr<KS> make_vw(double sg) {
    VWArr<KS> a{};
    double tmp[KS] = {};
    double sum = 0.0;
    for (int t = 0; t < KS; ++t) {
        const double ax = (double)(t - KS / 2);
        tmp[t] = cexp_(-(ax * ax) / (2.0 * sg * sg));
        sum += tmp[t];
    }
    for (int i = 0; i < VWArr<KS>::TPAD + 16; ++i) a.w[i] = 0.0f;
    for (int t = 0; t < KS; ++t) a.w[16 + t] = (float)(tmp[t] / sum);
    return a;
}

__device__ constexpr VWArr<7>   VW0 = make_vw<7>(0.6);
__device__ constexpr VWArr<9>   VW1 = make_vw<9>(1.2);
__device__ constexpr VWArr<17>  VW2 = make_vw<17>(2.4);
__device__ constexpr VWArr<31>  VW3 = make_vw<31>(4.8);
__device__ constexpr VWArr<59>  VW4 = make_vw<59>(9.6);
__device__ constexpr VWArr<117> VW5 = make_vw<117>(19.2);

// ---------------- vertical blur: 16 rows x float4 per thread ----------------
template<int KS, int PD>
__device__ __forceinline__ void vpass16(const float4* __restrict__ img4,
                                        float4* __restrict__ dst,
                                        int xt, int y0, const float* __restrict__ vw)
{
    constexpr int TPAD = (KS + 30) & ~15;
    float4 acc[16];
#pragma unroll
    for (int j = 0; j < 16; ++j) acc[j] = make_float4(0.f, 0.f, 0.f, 0.f);

    float ww[16];                      // window low half: ww[m] == vw[tb+m]
#pragma unroll
    for (int m = 0; m < 16; ++m) ww[m] = vw[m];

#pragma unroll 1
    for (int tb = 0; tb < TPAD; tb += 16) {
        float wn[16];                  // window high half: wn[k] == vw[tb+16+k]
#pragma unroll
        for (int k = 0; k < 16; ++k) wn[k] = vw[tb + 16 + k];
#pragma unroll
        for (int k = 0; k < 16; ++k) {
            const int yi = refl(y0 - PD + tb + k, HH);
            const float4 v = img4[(size_t)yi * (WW / 4) + xt];
#pragma unroll
            for (int j = 0; j < 16; ++j) {
                const int mi = 16 + k - j;               // 1..31, compile-time
                const float wt = (mi < 16) ? ww[mi] : wn[mi - 16];
                acc[j].x = fmaf(wt, v.x, acc[j].x);
                acc[j].y = fmaf(wt, v.y, acc[j].y);
                acc[j].z = fmaf(wt, v.z, acc[j].z);
                acc[j].w = fmaf(wt, v.w, acc[j].w);
            }
        }
#pragma unroll
        for (int m = 0; m < 16; ++m) ww[m] = wn[m];      // shift window
    }
#pragma unroll
    for (int j = 0; j < 16; ++j) dst[(size_t)(y0 + j) * (WW / 4) + xt] = acc[j];
}

// 1-D grid, XCD-swizzled: n = k*8 + xcd; per-XCD phase works on ONE channel
// image (1 MB) -> img re-reads hit that XCD's 4 MB L2 instead of streaming L3.
// 4608 = 8 xcd * 3 bcg * (6 scales * 32 ygroups)
__global__ __launch_bounds__(128) void vpass6_kernel(const float* __restrict__ img,
                                                     float* __restrict__ out)
{
    const int n   = blockIdx.x;
    const int xcd = n & 7;
    const int k   = n >> 3;              // 0..575
    const int bcg = k / 192;             // 0..2
    const int rem = k - bcg * 192;
    const int s   = rem >> 5;            // 0..5
    const int y0  = (rem & 31) << 4;
    const int bc  = bcg * 8 + xcd;       // 0..23
    const int xt  = threadIdx.x;         // 0..127 (float4 col)
    const int b = bc / CH, c = bc - b * CH;
    const float4* img4 = (const float4*)img + (size_t)bc * (HWX / 4);
    float4* dst = (float4*)out + ((size_t)((b * NSLOT + s + 1) * CH) + c) * (HWX / 4);
    switch (s) {
        case 0: vpass16<  7,  3>(img4, dst, xt, y0, VW0.w); break;
        case 1: vpass16<  9,  4>(img4, dst, xt, y0, VW1.w); break;
        case 2: vpass16< 17,  8>(img4, dst, xt, y0, VW2.w); break;
        case 3: vpass16< 31, 15>(img4, dst, xt, y0, VW3.w); break;
        case 4: vpass16< 59, 29>(img4, dst, xt, y0, VW4.w); break;
        default:vpass16<117, 58>(img4, dst, xt, y0, VW5.w); break;
    }
}

// ---------------- horizontal blur: 4 px/thread, 6-slot rolling window, prefetch-3 ----------
// lrow[i] = v[i - PDA]; output px 4*xt+j = sum_t W[8+t]*lrow[4*xt+j+t], t<NT (KSE taps)
template<int KSE>
__device__ __forceinline__ float4 hblur6(const float* __restrict__ lrow, int xt,
                                         const WArr<KSE>& W)
{
    constexpr int NT = (KSE + 3) & ~3;
    constexpr int G  = NT / 4;           // tap groups
    constexpr int NR = G + 2;            // float4 slots needed: 0..G+1
    const float4* l4 = (const float4*)lrow;
    float cb[24];                        // 6 rolling float4 slots
#pragma unroll
    for (int s = 0; s < (NR < 4 ? NR : 4); ++s) {   // up-front prefetch
        const float4 t = l4[xt + s];
        cb[(s % 6) * 4 + 0] = t.x; cb[(s % 6) * 4 + 1] = t.y;
        cb[(s % 6) * 4 + 2] = t.z; cb[(s % 6) * 4 + 3] = t.w;
    }
    float a[4] = {0.f, 0.f, 0.f, 0.f};
#pragma unroll
    for (int g = 0; g < G; ++g) {
        if (g + 4 < NR) {                // read 3 groups ahead (folds at unroll)
            const int sl = (g + 4) % 6;
            const float4 t = l4[xt + g + 4];
            cb[sl * 4 + 0] = t.x; cb[sl * 4 + 1] = t.y;
            cb[sl * 4 + 2] = t.z; cb[sl * 4 + 3] = t.w;
        }
#pragma unroll
        for (int tt = 0; tt < 4; ++tt) {
            const float wt = W.w[8 + 4 * g + tt];        // compile-time constant
#pragma unroll
            for (int j = 0; j < 4; ++j) {
                const int q    = tt + j;                 // 0..6
                const int slot = (g + (q >> 2)) % 6;
                a[j] = fmaf(wt, cb[slot * 4 + (q & 3)], a[j]);
            }
        }
    }
    return make_float4(a[0], a[1], a[2], a[3]);
}

// ---------------- fused h-pass + DoG diff, in-place on out ---------------------------------
// One row per 128-thread block. LDS layout (floats), left pad PDA (mult of 4):
// s:      0     1     2     3     4     5
// PDA:    4     4     8    16    32    60
// OFF:    0   524  1052  1588  2136  2716
// LEN:  524   528   536   548   580   636   (= NT + 516)
#define LDSROW 3352   // 13408 B/block -> 11 blocks/CU (22 waves)

// All-vector staging: one b128 bulk store + tiny scalar halos (conflict-free).
template<int OFF, int LEN, int PDA>
__device__ __forceinline__ void stage_row(float* __restrict__ L,
                                          const float* __restrict__ g, int xt)
{
    ((float4*)(L + OFF + PDA))[xt] = ((const float4*)g)[xt];
    if (xt < PDA) L[OFF + xt] = g[PDA - xt];                      // left reflect
    for (int i = PDA + 512 + xt; i < LEN; i += 128)               // right reflect
        L[OFF + i] = g[1022 - (i - PDA)];
}

__device__ __forceinline__ float4 f4sub(float4 a, float4 b) {
    return make_float4(a.x - b.x, a.y - b.y, a.z - b.z, a.w - b.w);
}

// 1-D grid, XCD-swizzled consistently with vpass (same bc -> same XCD, so the
// v-blurred slots are read on the XCD whose L2 holds their tail).
// 12288 = 8 xcd * 3 bcg * 512 rows
__global__ __launch_bounds__(128) void hdiff6_kernel(const float* __restrict__ img,
                                                     float* __restrict__ out)
{
    __shared__ __align__(16) float L[LDSROW];
    const int n   = blockIdx.x;
    const int xcd = n & 7;
    const int k   = n >> 3;              // 0..1535
    const int bcg = k >> 9;              // 0..2
    const int y   = k & 511;
    const int bc  = bcg * 8 + xcd;       // 0..23
    const int xt  = threadIdx.x;         // 0..127
    const int b = bc / CH, c = bc - b * CH;

    const size_t rowoff = (size_t)y * WW;
    // g0 = img row, own pixels only; issue before the barrier so it overlaps staging
    const float4 gp0 = ((const float4*)(img + (size_t)bc * HWX + rowoff))[xt];

    // stage the 6 v-blurred rows from out slots 1..6
    constexpr size_t SSTR = (size_t)CH * HWX;     // slot stride in floats
    const float* g1 = out + ((size_t)((b * NSLOT + 1) * CH) + c) * HWX + rowoff;
    stage_row<   0, 524,  4>(L, g1,            xt);
    stage_row< 524, 528,  4>(L, g1 + 1 * SSTR, xt);
    stage_row<1052, 536,  8>(L, g1 + 2 * SSTR, xt);
    stage_row<1588, 548, 16>(L, g1 + 3 * SSTR, xt);
    stage_row<2136, 580, 32>(L, g1 + 4 * SSTR, xt);
    stage_row<2716, 636, 60>(L, g1 + 5 * SSTR, xt);
    __syncthreads();

    float4* out4 = (float4*)out;
    const size_t pbase = (size_t)y * (WW / 4) + xt;
#define OSL(s) (out4 + ((size_t)((b * NSLOT + (s)) * CH) + c) * (HWX / 4) + pbase)

    float4 gp = gp0;
    float4 g;
    g = hblur6<  8>(L +    0, xt, CW0); *OSL(0) = f4sub(g, gp); gp = g;
    g = hblur6<  9>(L +  524, xt, CW1); *OSL(1) = f4sub(g, gp); gp = g;
    g = hblur6< 17>(L + 1052, xt, CW2); *OSL(2) = f4sub(g, gp); gp = g;
    g = hblur6< 32>(L + 1588, xt, CW3); *OSL(3) = f4sub(g, gp); gp = g;
    g = hblur6< 62>(L + 2136, xt, CW4); *OSL(4) = f4sub(g, gp); gp = g;
    g = hblur6<119>(L + 2716, xt, CW5); *OSL(5) = f4sub(g, gp);
    *OSL(6) = g;
#undef OSL
}

// ---------------- host ----------------------------------------------------------------------
extern "C" void kernel_launch(void* const* d_in, const int* in_sizes, int n_in,
                              void* d_out, int out_size, void* d_ws, size_t ws_size,
                              hipStream_t stream) {
    const float* img = (const float*)d_in[0];
    float* out = (float*)d_out;

    // pass 1: vertical blur img -> out slots 1..6 (XCD-swizzled 1-D grid)
    hipLaunchKernelGGL(vpass6_kernel, dim3(4608), dim3(128), 0, stream, img, out);

    // pass 2: horizontal blur + DoG diff chain, in-place on out (XCD-swizzled)
    hipLaunchKernelGGL(hdiff6_kernel, dim3(12288), dim3(128), 0, stream, img, out);
}